// Round 1
// baseline (652.706 us; speedup 1.0000x reference)
//
#include <hip/hip_runtime.h>

#define NN 50000
#define NE 800000
#define NG 512
#define FIN 9
#define D1 64
#define D2 32

static inline int cdiv(int a, int b) { return (a + b - 1) / b; }

// ---- degree count for both edge lists ----
__global__ void k_deg(const int* __restrict__ ei, const int* __restrict__ adj,
                      int* __restrict__ deg_e, int* __restrict__ deg_a) {
  int e = blockIdx.x * blockDim.x + threadIdx.x;
  if (e < NE) {
    atomicAdd(&deg_e[ei[NE + e]], 1);
    atomicAdd(&deg_a[adj[NE + e]], 1);
  }
}

// ---- 3-phase exclusive scan over NN ints (196 blocks of 256) ----
__global__ void k_scan_a(const int* __restrict__ deg, int* __restrict__ off,
                         int* __restrict__ partial) {
  __shared__ int tmp[256];
  int i = blockIdx.x * 256 + threadIdx.x;
  int v = (i < NN) ? deg[i] : 0;
  tmp[threadIdx.x] = v;
  __syncthreads();
  for (int d = 1; d < 256; d <<= 1) {
    int t = (threadIdx.x >= d) ? tmp[threadIdx.x - d] : 0;
    __syncthreads();
    tmp[threadIdx.x] += t;
    __syncthreads();
  }
  if (i < NN) off[i] = tmp[threadIdx.x] - v;  // exclusive within block
  if (threadIdx.x == 255) partial[blockIdx.x] = tmp[255];
}

__global__ void k_scan_b(int* __restrict__ partial, int nb) {
  __shared__ int tmp[256];
  int v = (threadIdx.x < nb) ? partial[threadIdx.x] : 0;
  tmp[threadIdx.x] = v;
  __syncthreads();
  for (int d = 1; d < 256; d <<= 1) {
    int t = (threadIdx.x >= d) ? tmp[threadIdx.x - d] : 0;
    __syncthreads();
    tmp[threadIdx.x] += t;
    __syncthreads();
  }
  if (threadIdx.x < nb) partial[threadIdx.x] = tmp[threadIdx.x] - v;  // exclusive
}

__global__ void k_scan_c(int* __restrict__ off, const int* __restrict__ partial,
                         int* __restrict__ cur) {
  int i = blockIdx.x * 256 + threadIdx.x;
  if (i < NN) {
    int o = off[i] + partial[blockIdx.x];
    off[i] = o;
    cur[i] = o;
  }
  if (i == 0) off[NN] = NE;
}

// ---- CSR fill: bucket sources by dst ----
__global__ void k_fill(const int* __restrict__ edges, int* __restrict__ cur,
                       int* __restrict__ srcbuf) {
  int e = blockIdx.x * blockDim.x + threadIdx.x;
  if (e < NE) {
    int s = edges[e], d = edges[NE + e];
    int pos = atomicAdd(&cur[d], 1);
    srcbuf[pos] = s;
  }
}

__global__ void k_dis(const int* __restrict__ deg_e, float* __restrict__ dis) {
  int i = blockIdx.x * blockDim.x + threadIdx.x;
  if (i < NN) dis[i] = rsqrtf(1.0f + (float)deg_e[i]);
}

// ---- xw1 = x @ W1  [NN,9]@[9,64] — one wave per node, lane = out feature ----
__global__ void k_xw1(const float* __restrict__ x, const float* __restrict__ W1,
                      float* __restrict__ xw1) {
  int gid = blockIdx.x * blockDim.x + threadIdx.x;
  int i = gid >> 6, j = gid & 63;
  if (i >= NN) return;
  const float* xr = x + i * FIN;
  float acc = 0.f;
#pragma unroll
  for (int k = 0; k < FIN; ++k) acc += xr[k] * W1[k * D1 + j];
  xw1[i * D1 + j] = acc;
}

// ---- GCN aggregate: out = relu(b + xw[i]*dis[i]^2 + dis[i]*sum_src xw[src]*dis[src]) ----
template <int F>
__global__ void k_gcn(const float* __restrict__ xw, const float* __restrict__ dis,
                      const int* __restrict__ off, const int* __restrict__ srcs,
                      const float* __restrict__ b, float* __restrict__ hout) {
  int gid = blockIdx.x * blockDim.x + threadIdx.x;
  int i = gid / F, j = gid % F;
  if (i >= NN) return;
  float di = dis[i];
  float self = xw[i * F + j];
  int s = off[i], e = off[i + 1];
  float acc = 0.f;
  for (int t = s; t < e; ++t) {
    int sn = srcs[t];
    acc += xw[sn * F + j] * dis[sn];
  }
  float o = b[j] + self * di * di + di * acc;
  hout[i * F + j] = fmaxf(o, 0.f);
}

// ---- A/B precompute for EdgeConv: A = h@W[:FI], B = h@W[FI:] ----
template <int FI, int FO>
__global__ void k_ab(const float* __restrict__ h, const float* __restrict__ eW,
                     float* __restrict__ A, float* __restrict__ B) {
  __shared__ float w[2 * FI * FO];
  for (int t = threadIdx.x; t < 2 * FI * FO; t += blockDim.x) w[t] = eW[t];
  __syncthreads();
  int gid = blockIdx.x * blockDim.x + threadIdx.x;
  int i = gid / FO, j = gid % FO;
  if (i >= NN) return;
  float a = 0.f, bb = 0.f;
#pragma unroll
  for (int k = 0; k < FI; ++k) {
    float hv = h[i * FI + k];
    a += hv * w[k * FO + j];
    bb += hv * w[(FI + k) * FO + j];
  }
  A[i * FO + j] = a;
  B[i * FO + j] = bb;
}

// ---- EdgeConv aggregate: max_src relu(A[i] - B[i] + eb + B[src]), empty -> 0 ----
template <int F>
__global__ void k_edge(const float* __restrict__ A, const float* __restrict__ B,
                       const float* __restrict__ eb, const int* __restrict__ off,
                       const int* __restrict__ srcs, float* __restrict__ hout) {
  int gid = blockIdx.x * blockDim.x + threadIdx.x;
  int i = gid / F, j = gid % F;
  if (i >= NN) return;
  float base = A[i * F + j] - B[i * F + j] + eb[j];
  int s = off[i], e = off[i + 1];
  float m = 0.f;
  for (int t = s; t < e; ++t) {
    int sn = srcs[t];
    m = fmaxf(m, base + B[sn * F + j]);
  }
  hout[i * F + j] = m;
}

// ---- xw2 = h2 @ W2  [NN,64]@[64,32] ----
__global__ void k_xw2(const float* __restrict__ h2, const float* __restrict__ W2,
                      float* __restrict__ xw2) {
  __shared__ float w[D1 * D2];
  for (int t = threadIdx.x; t < D1 * D2; t += blockDim.x) w[t] = W2[t];
  __syncthreads();
  int gid = blockIdx.x * blockDim.x + threadIdx.x;
  int i = gid >> 5, j = gid & 31;
  if (i >= NN) return;
  float acc = 0.f;
#pragma unroll
  for (int k = 0; k < D1; ++k) acc += h2[i * D1 + k] * w[k * D2 + j];
  xw2[i * D2 + j] = acc;
}

// ---- FC + segment mean-pool accumulation ----
__global__ void k_final(const float* __restrict__ h4, const float* __restrict__ fcW,
                        const float* __restrict__ fcb, const int* __restrict__ batch,
                        float* __restrict__ sums, float* __restrict__ cnt) {
  int i = blockIdx.x * blockDim.x + threadIdx.x;
  if (i >= NN) return;
  float acc = fcb[0];
#pragma unroll
  for (int k = 0; k < D2; ++k) acc += h4[i * D2 + k] * fcW[k];
  int g = batch[i];
  atomicAdd(&sums[g], acc);
  atomicAdd(&cnt[g], 1.0f);
}

__global__ void k_out(const float* __restrict__ sums, const float* __restrict__ cnt,
                      float* __restrict__ out) {
  int g = blockIdx.x * blockDim.x + threadIdx.x;
  if (g < NG) out[g] = sums[g] / fmaxf(cnt[g], 1.0f);
}

extern "C" void kernel_launch(void* const* d_in, const int* in_sizes, int n_in,
                              void* d_out, int out_size, void* d_ws, size_t ws_size,
                              hipStream_t stream) {
  const float* x = (const float*)d_in[0];
  const int* ei = (const int*)d_in[1];
  const int* adj = (const int*)d_in[2];
  const int* batch = (const int*)d_in[3];
  const float* W1 = (const float*)d_in[4];
  const float* b1 = (const float*)d_in[5];
  const float* eW1 = (const float*)d_in[6];
  const float* eb1 = (const float*)d_in[7];
  const float* W2 = (const float*)d_in[8];
  const float* b2 = (const float*)d_in[9];
  const float* eW2 = (const float*)d_in[10];
  const float* eb2 = (const float*)d_in[11];
  const float* fcW = (const float*)d_in[12];
  const float* fcb = (const float*)d_in[13];
  float* out = (float*)d_out;

  // ---- workspace bump allocator (256B aligned) ----
  char* ws = (char*)d_ws;
  size_t p = 0;
  auto alloc = [&](size_t bytes) -> void* {
    void* r = ws + p;
    p = (p + bytes + 255) & ~(size_t)255;
    return r;
  };
  // zeroed prefix
  int* deg_e = (int*)alloc(NN * 4);
  int* deg_a = (int*)alloc(NN * 4);
  float* sums = (float*)alloc(NG * 4);
  float* cnt = (float*)alloc(NG * 4);
  size_t zero_bytes = p;
  // rest
  int* off_e = (int*)alloc((NN + 1) * 4);
  int* cur_e = (int*)alloc(NN * 4);
  int* src_e = (int*)alloc(NE * 4);
  int* off_a = (int*)alloc((NN + 1) * 4);
  int* cur_a = (int*)alloc(NN * 4);
  int* src_a = (int*)alloc(NE * 4);
  int* part_e = (int*)alloc(256 * 4);
  int* part_a = (int*)alloc(256 * 4);
  float* dis = (float*)alloc(NN * 4);
  float* buf0 = (float*)alloc((size_t)NN * D1 * 4);
  float* buf1 = (float*)alloc((size_t)NN * D1 * 4);
  float* buf2 = (float*)alloc((size_t)NN * D1 * 4);
  float* buf3 = (float*)alloc((size_t)NN * D1 * 4);
  float* buf4 = (float*)alloc((size_t)NN * D1 * 4);

  const int NB = cdiv(NN, 256);  // 196

  hipMemsetAsync(d_ws, 0, zero_bytes, stream);

  k_deg<<<cdiv(NE, 256), 256, 0, stream>>>(ei, adj, deg_e, deg_a);

  k_scan_a<<<NB, 256, 0, stream>>>(deg_e, off_e, part_e);
  k_scan_a<<<NB, 256, 0, stream>>>(deg_a, off_a, part_a);
  k_scan_b<<<1, 256, 0, stream>>>(part_e, NB);
  k_scan_b<<<1, 256, 0, stream>>>(part_a, NB);
  k_scan_c<<<NB, 256, 0, stream>>>(off_e, part_e, cur_e);
  k_scan_c<<<NB, 256, 0, stream>>>(off_a, part_a, cur_a);

  k_fill<<<cdiv(NE, 256), 256, 0, stream>>>(ei, cur_e, src_e);
  k_fill<<<cdiv(NE, 256), 256, 0, stream>>>(adj, cur_a, src_a);
  k_dis<<<NB, 256, 0, stream>>>(deg_e, dis);

  // layer 1: GCN(9->64) + relu
  k_xw1<<<cdiv(NN * D1, 256), 256, 0, stream>>>(x, W1, buf0);
  k_gcn<D1><<<cdiv(NN * D1, 256), 256, 0, stream>>>(buf0, dis, off_e, src_e, b1, buf1);
  // layer 2: EdgeConv(64->64)
  k_ab<D1, D1><<<cdiv(NN * D1, 256), 256, 0, stream>>>(buf1, eW1, buf2, buf3);
  k_edge<D1><<<cdiv(NN * D1, 256), 256, 0, stream>>>(buf2, buf3, eb1, off_a, src_a, buf4);
  // layer 3: GCN(64->32) + relu
  k_xw2<<<cdiv(NN * D2, 256), 256, 0, stream>>>(buf4, W2, buf0);
  k_gcn<D2><<<cdiv(NN * D2, 256), 256, 0, stream>>>(buf0, dis, off_e, src_e, b2, buf1);
  // layer 4: EdgeConv(32->32)
  float* A2 = buf2;
  float* B2 = buf2 + (size_t)NN * D2;
  k_ab<D2, D2><<<cdiv(NN * D2, 256), 256, 0, stream>>>(buf1, eW2, A2, B2);
  k_edge<D2><<<cdiv(NN * D2, 256), 256, 0, stream>>>(A2, B2, eb2, off_a, src_a, buf3);
  // FC + mean pool
  k_final<<<NB, 256, 0, stream>>>(buf3, fcW, fcb, batch, sums, cnt);
  k_out<<<cdiv(NG, 256), 256, 0, stream>>>(sums, cnt, out);
}

// Round 3
// 544.734 us; speedup vs baseline: 1.1982x; 1.1982x over previous
//
#include <hip/hip_runtime.h>

#define NN 50000
#define NE 800000
#define NG 512
#define FIN 9
#define D1 64
#define D2 32

static inline int cdiv(int a, int b) { return (a + b - 1) / b; }

// ---- degree count for both edge lists ----
__global__ void k_deg(const int* __restrict__ ei, const int* __restrict__ adj,
                      int* __restrict__ deg_e, int* __restrict__ deg_a) {
  int e = blockIdx.x * blockDim.x + threadIdx.x;
  if (e < NE) {
    atomicAdd(&deg_e[ei[NE + e]], 1);
    atomicAdd(&deg_a[adj[NE + e]], 1);
  }
}

// ---- 3-phase exclusive scan over NN ints ----
__global__ void k_scan_a(const int* __restrict__ deg, int* __restrict__ off,
                         int* __restrict__ partial) {
  __shared__ int tmp[256];
  int i = blockIdx.x * 256 + threadIdx.x;
  int v = (i < NN) ? deg[i] : 0;
  tmp[threadIdx.x] = v;
  __syncthreads();
  for (int d = 1; d < 256; d <<= 1) {
    int t = (threadIdx.x >= d) ? tmp[threadIdx.x - d] : 0;
    __syncthreads();
    tmp[threadIdx.x] += t;
    __syncthreads();
  }
  if (i < NN) off[i] = tmp[threadIdx.x] - v;
  if (threadIdx.x == 255) partial[blockIdx.x] = tmp[255];
}

__global__ void k_scan_b(int* __restrict__ partial, int nb) {
  __shared__ int tmp[256];
  int v = (threadIdx.x < nb) ? partial[threadIdx.x] : 0;
  tmp[threadIdx.x] = v;
  __syncthreads();
  for (int d = 1; d < 256; d <<= 1) {
    int t = (threadIdx.x >= d) ? tmp[threadIdx.x - d] : 0;
    __syncthreads();
    tmp[threadIdx.x] += t;
    __syncthreads();
  }
  if (threadIdx.x < nb) partial[threadIdx.x] = tmp[threadIdx.x] - v;
}

__global__ void k_scan_c(int* __restrict__ off, const int* __restrict__ partial,
                         int* __restrict__ cur) {
  int i = blockIdx.x * 256 + threadIdx.x;
  if (i < NN) {
    int o = off[i] + partial[blockIdx.x];
    off[i] = o;
    cur[i] = o;
  }
  if (i == 0) off[NN] = NE;
}

// ---- CSR fill: bucket sources by dst ----
__global__ void k_fill(const int* __restrict__ edges, int* __restrict__ cur,
                       int* __restrict__ srcbuf) {
  int e = blockIdx.x * blockDim.x + threadIdx.x;
  if (e < NE) {
    int s = edges[e], d = edges[NE + e];
    int pos = atomicAdd(&cur[d], 1);
    srcbuf[pos] = s;
  }
}

__global__ void k_dis(const int* __restrict__ deg_e, float* __restrict__ dis) {
  int i = blockIdx.x * blockDim.x + threadIdx.x;
  if (i < NN) dis[i] = rsqrtf(1.0f + (float)deg_e[i]);
}

// ---- xws1 = (x @ W1) * dis  [NN,9]@[9,64] — lane = out feature ----
__global__ void k_xw1(const float* __restrict__ x, const float* __restrict__ W1,
                      const float* __restrict__ dis, float* __restrict__ xws1) {
  int gid = blockIdx.x * blockDim.x + threadIdx.x;
  int i = gid >> 6, j = gid & 63;
  if (i >= NN) return;
  const float* xr = x + i * FIN;
  float acc = 0.f;
#pragma unroll
  for (int k = 0; k < FIN; ++k) acc += xr[k] * W1[k * D1 + j];
  xws1[i * D1 + j] = acc * dis[i];
}

// ============================================================================
// Register-tiled fp32 GEMM: C[NN, FOT] = H[NN, FI] @ Wcat[FI, FOT]
// MODE 0: Wcat = W (row-major [FI][FOT]); writes OA[n*FOT+j]
// MODE 1: Wcat = [eW[:FI] | eW[FI:]] (eW is [2*FI][FO], FOT=2*FO);
//         writes A=OA[n*FO+j], B=OB[n*FO+j-FO]
// SCALE: multiply output row n by dis[n]
// Block: 256 threads; tile = BN nodes x FOT cols; thread tile = TM x TN.
// ============================================================================
template <int FI, int FOT, int MODE, bool SCALE>
__global__ __launch_bounds__(256) void k_gemm(const float* __restrict__ H,
                                              const float* __restrict__ W,
                                              const float* __restrict__ dis,
                                              float* __restrict__ OA,
                                              float* __restrict__ OB) {
  constexpr int TM = 4;
  constexpr int TN = (FOT >= 64) ? 4 : 2;
  constexpr int BN = 1024 * TN / FOT;  // (BN/TM)*(FOT/TN) == 256
  constexpr int LDH = BN + 1;          // pad: conflict-free transpose write
  constexpr int FO = FOT / 2;          // only used for MODE 1
  __shared__ float ht[FI][LDH];
  __shared__ float wc[FI][FOT];

  // stage weights (concat-rearranged for MODE 1)
  for (int t = threadIdx.x; t < FI * FOT; t += 256) {
    int k = t / FOT, j = t % FOT;
    float v;
    if (MODE == 1)
      v = (j < FO) ? W[k * FO + j] : W[(FI + k) * FO + (j - FO)];
    else
      v = W[k * FOT + j];
    wc[k][j] = v;
  }
  // stage h^T: read coalesced along k, write transposed (pad -> spread banks)
  int node0 = blockIdx.x * BN;
  for (int t = threadIdx.x; t < BN * FI; t += 256) {
    int n = t / FI, k = t % FI;
    int nn = node0 + n;
    ht[k][n] = (nn < NN) ? H[(size_t)nn * FI + k] : 0.f;
  }
  __syncthreads();

  int tn = threadIdx.x % (FOT / TN);
  int tm = threadIdx.x / (FOT / TN);
  int j0 = tn * TN, n0 = tm * TM;

  float acc[TM][TN];
#pragma unroll
  for (int m = 0; m < TM; ++m)
#pragma unroll
    for (int q = 0; q < TN; ++q) acc[m][q] = 0.f;

  for (int k = 0; k < FI; ++k) {
    float wv[TN];
    if (TN == 4) {
      float4 w4 = *(const float4*)&wc[k][j0];
      wv[0] = w4.x; wv[1] = w4.y; wv[2] = w4.z; wv[3] = w4.w;
    } else {
      float2 w2 = *(const float2*)&wc[k][j0];
      wv[0] = w2.x; wv[1] = w2.y;
    }
    float hv[TM];
#pragma unroll
    for (int m = 0; m < TM; ++m) hv[m] = ht[k][n0 + m];
#pragma unroll
    for (int m = 0; m < TM; ++m)
#pragma unroll
      for (int q = 0; q < TN; ++q) acc[m][q] += hv[m] * wv[q];
  }

  // epilogue
#pragma unroll
  for (int m = 0; m < TM; ++m) {
    int n = node0 + n0 + m;
    if (n >= NN) break;
    float sc = SCALE ? dis[n] : 1.0f;
    if (MODE == 1) {
      float* dst = (j0 < FO) ? (OA + (size_t)n * FO + j0)
                             : (OB + (size_t)n * FO + (j0 - FO));
      if (TN == 4) {
        float4 o = {acc[m][0] * sc, acc[m][1] * sc, acc[m][2] * sc, acc[m][3] * sc};
        *(float4*)dst = o;
      } else {
        float2 o = {acc[m][0] * sc, acc[m][1] * sc};
        *(float2*)dst = o;
      }
    } else {
      float* dst = OA + (size_t)n * FOT + j0;
      if (TN == 4) {
        float4 o = {acc[m][0] * sc, acc[m][1] * sc, acc[m][2] * sc, acc[m][3] * sc};
        *(float4*)dst = o;
      } else {
        float2 o = {acc[m][0] * sc, acc[m][1] * sc};
        *(float2*)dst = o;
      }
    }
  }
}

// ---- GCN aggregate on pre-scaled features:
//      out = relu(b + dis[i] * (xws[i] + sum_src xws[src])) ----
template <int F>
__global__ void k_gcn(const float* __restrict__ xws, const float* __restrict__ dis,
                      const int* __restrict__ off, const int* __restrict__ srcs,
                      const float* __restrict__ b, float* __restrict__ hout) {
  int gid = blockIdx.x * blockDim.x + threadIdx.x;
  int i = gid / F, j = gid % F;
  if (i >= NN) return;
  float acc = xws[(size_t)i * F + j];
  int s = off[i], e = off[i + 1];
  int t = s;
  for (; t + 1 < e; t += 2) {
    int s0 = srcs[t], s1 = srcs[t + 1];
    acc += xws[(size_t)s0 * F + j];
    acc += xws[(size_t)s1 * F + j];
  }
  if (t < e) acc += xws[(size_t)srcs[t] * F + j];
  float o = b[j] + dis[i] * acc;
  hout[(size_t)i * F + j] = fmaxf(o, 0.f);
}

// ---- EdgeConv aggregate: max_src relu(A[i] - B[i] + eb + B[src]), empty -> 0 ----
template <int F>
__global__ void k_edge(const float* __restrict__ A, const float* __restrict__ B,
                       const float* __restrict__ eb, const int* __restrict__ off,
                       const int* __restrict__ srcs, float* __restrict__ hout) {
  int gid = blockIdx.x * blockDim.x + threadIdx.x;
  int i = gid / F, j = gid % F;
  if (i >= NN) return;
  float base = A[(size_t)i * F + j] - B[(size_t)i * F + j] + eb[j];
  int s = off[i], e = off[i + 1];
  float m = 0.f;
  int t = s;
  for (; t + 1 < e; t += 2) {
    int s0 = srcs[t], s1 = srcs[t + 1];
    m = fmaxf(m, base + B[(size_t)s0 * F + j]);
    m = fmaxf(m, base + B[(size_t)s1 * F + j]);
  }
  if (t < e) m = fmaxf(m, base + B[(size_t)srcs[t] * F + j]);
  hout[(size_t)i * F + j] = m;
}

// ---- FC + segment mean-pool accumulation ----
__global__ void k_final(const float* __restrict__ h4, const float* __restrict__ fcW,
                        const float* __restrict__ fcb, const int* __restrict__ batch,
                        float* __restrict__ sums, float* __restrict__ cnt) {
  int i = blockIdx.x * blockDim.x + threadIdx.x;
  if (i >= NN) return;
  float acc = fcb[0];
#pragma unroll
  for (int k = 0; k < D2; ++k) acc += h4[(size_t)i * D2 + k] * fcW[k];
  int g = batch[i];
  atomicAdd(&sums[g], acc);
  atomicAdd(&cnt[g], 1.0f);
}

__global__ void k_out(const float* __restrict__ sums, const float* __restrict__ cnt,
                      float* __restrict__ out) {
  int g = blockIdx.x * blockDim.x + threadIdx.x;
  if (g < NG) out[g] = sums[g] / fmaxf(cnt[g], 1.0f);
}

extern "C" void kernel_launch(void* const* d_in, const int* in_sizes, int n_in,
                              void* d_out, int out_size, void* d_ws, size_t ws_size,
                              hipStream_t stream) {
  const float* x = (const float*)d_in[0];
  const int* ei = (const int*)d_in[1];
  const int* adj = (const int*)d_in[2];
  const int* batch = (const int*)d_in[3];
  const float* W1 = (const float*)d_in[4];
  const float* b1 = (const float*)d_in[5];
  const float* eW1 = (const float*)d_in[6];
  const float* eb1 = (const float*)d_in[7];
  const float* W2 = (const float*)d_in[8];
  const float* b2 = (const float*)d_in[9];
  const float* eW2 = (const float*)d_in[10];
  const float* eb2 = (const float*)d_in[11];
  const float* fcW = (const float*)d_in[12];
  const float* fcb = (const float*)d_in[13];
  float* out = (float*)d_out;

  // ---- workspace bump allocator (256B aligned) ----
  char* ws = (char*)d_ws;
  size_t p = 0;
  auto alloc = [&](size_t bytes) -> void* {
    void* r = ws + p;
    p = (p + bytes + 255) & ~(size_t)255;
    return r;
  };
  // zeroed prefix
  int* deg_e = (int*)alloc(NN * 4);
  int* deg_a = (int*)alloc(NN * 4);
  float* sums = (float*)alloc(NG * 4);
  float* cnt = (float*)alloc(NG * 4);
  size_t zero_bytes = p;
  // rest
  int* off_e = (int*)alloc((NN + 1) * 4);
  int* cur_e = (int*)alloc(NN * 4);
  int* src_e = (int*)alloc(NE * 4);
  int* off_a = (int*)alloc((NN + 1) * 4);
  int* cur_a = (int*)alloc(NN * 4);
  int* src_a = (int*)alloc(NE * 4);
  int* part_e = (int*)alloc(256 * 4);
  int* part_a = (int*)alloc(256 * 4);
  float* dis = (float*)alloc(NN * 4);
  float* buf0 = (float*)alloc((size_t)NN * D1 * 4);
  float* buf1 = (float*)alloc((size_t)NN * D1 * 4);
  float* buf2 = (float*)alloc((size_t)NN * D1 * 4);
  float* buf3 = (float*)alloc((size_t)NN * D1 * 4);
  float* buf4 = (float*)alloc((size_t)NN * D1 * 4);

  const int NB = cdiv(NN, 256);

  hipMemsetAsync(d_ws, 0, zero_bytes, stream);

  k_deg<<<cdiv(NE, 256), 256, 0, stream>>>(ei, adj, deg_e, deg_a);

  k_scan_a<<<NB, 256, 0, stream>>>(deg_e, off_e, part_e);
  k_scan_a<<<NB, 256, 0, stream>>>(deg_a, off_a, part_a);
  k_scan_b<<<1, 256, 0, stream>>>(part_e, NB);
  k_scan_b<<<1, 256, 0, stream>>>(part_a, NB);
  k_scan_c<<<NB, 256, 0, stream>>>(off_e, part_e, cur_e);
  k_scan_c<<<NB, 256, 0, stream>>>(off_a, part_a, cur_a);

  k_fill<<<cdiv(NE, 256), 256, 0, stream>>>(ei, cur_e, src_e);
  k_fill<<<cdiv(NE, 256), 256, 0, stream>>>(adj, cur_a, src_a);
  k_dis<<<NB, 256, 0, stream>>>(deg_e, dis);

  // layer 1: GCN(9->64) + relu   (xws1 = (x@W1)*dis)
  k_xw1<<<cdiv(NN * D1, 256), 256, 0, stream>>>(x, W1, dis, buf0);
  k_gcn<D1><<<cdiv(NN * D1, 256), 256, 0, stream>>>(buf0, dis, off_e, src_e, b1, buf1);

  // layer 2: EdgeConv(64->64): A,B = h@eW1 halves  (tiled GEMM)
  k_gemm<D1, 2 * D1, 1, false><<<cdiv(NN, 32), 256, 0, stream>>>(buf1, eW1, nullptr, buf2, buf3);
  k_edge<D1><<<cdiv(NN * D1, 256), 256, 0, stream>>>(buf2, buf3, eb1, off_a, src_a, buf4);

  // layer 3: GCN(64->32) + relu  (xws2 = (h@W2)*dis via GEMM epilogue)
  k_gemm<D1, D2, 0, true><<<cdiv(NN, 64), 256, 0, stream>>>(buf4, W2, dis, buf0, nullptr);
  k_gcn<D2><<<cdiv(NN * D2, 256), 256, 0, stream>>>(buf0, dis, off_e, src_e, b2, buf1);

  // layer 4: EdgeConv(32->32)
  float* A2 = buf2;
  float* B2 = buf2 + (size_t)NN * D2;
  k_gemm<D2, 2 * D2, 1, false><<<cdiv(NN, 64), 256, 0, stream>>>(buf1, eW2, nullptr, A2, B2);
  k_edge<D2><<<cdiv(NN * D2, 256), 256, 0, stream>>>(A2, B2, eb2, off_a, src_a, buf3);

  // FC + mean pool
  k_final<<<NB, 256, 0, stream>>>(buf3, fcW, fcb, batch, sums, cnt);
  k_out<<<cdiv(NG, 256), 256, 0, stream>>>(sums, cnt, out);
}